// Round 10
// baseline (238.781 us; speedup 1.0000x reference)
//
#include <hip/hip_runtime.h>
#include <math.h>
#include <stdint.h>

#define PI2 6.28318530717958647692f

typedef __bf16 bf16x8 __attribute__((ext_vector_type(8)));
typedef float f32x4 __attribute__((ext_vector_type(4)));

typedef __attribute__((address_space(1))) const void gvoid_t;
typedef __attribute__((address_space(3))) void lvoid_t;

__device__ __forceinline__ void g2l16(const void* g, void* l) {
    __builtin_amdgcn_global_load_lds(
        reinterpret_cast<gvoid_t*>(reinterpret_cast<uintptr_t>(g)),
        reinterpret_cast<lvoid_t*>(reinterpret_cast<uintptr_t>(l)),
        16, 0, 0);
}

__device__ __forceinline__ short f2bf(float f) {
    unsigned u = __float_as_uint(f);
    u += 0x7FFFu + ((u >> 16) & 1u);          // round-to-nearest-even
    return (short)(u >> 16);
}

__device__ __forceinline__ unsigned pack2bf(float a, float b) {
    return (unsigned)(unsigned short)f2bf(a) |
           ((unsigned)(unsigned short)f2bf(b) << 16);
}

__device__ __forceinline__ float bflo(unsigned v) { return __uint_as_float(v << 16); }
__device__ __forceinline__ float bfhi(unsigned v) { return __uint_as_float(v & 0xFFFF0000u); }

// XCD-locality swizzle (round-9): contiguous unit range per XCD.
__device__ __forceinline__ int xcd_swizzle(int blk, int G) {
    return (blk & 7) * (G >> 3) + (blk >> 3);
}

// ---------------------------------------------------------------------------
// Fused aux kernel, 8 elements per thread. 13312 blocks.
//   [0,        4194304): x_bf = bf16(x)                      1024x4096
//   [4194304, 12582912): B1   = DFT basis n=4096             2048x4096
//   [12582912,16777216): Vcat = [Vr|Vi]                      2048x2048
//   [16777216,18874368): B2t  = DFT basis n=2048 (T) * S[k]  2048x1024
//   [18874368,23068672): Ucat = [Ur|Ui]                      4096x1024
//   [23068672,27262976): out  = bias broadcast (f32)         1024x4096
// ---------------------------------------------------------------------------
__global__ __launch_bounds__(256) void aux_all8(
    const float* __restrict__ x,
    const float* __restrict__ Ur, const float* __restrict__ Ui,
    const float* __restrict__ S,
    const float* __restrict__ Vr, const float* __restrict__ Vi,
    short* __restrict__ x_bf, short* __restrict__ B1,
    short* __restrict__ Vcat, short* __restrict__ B2t,
    short* __restrict__ Ucat,
    const float* __restrict__ bias, float* __restrict__ outF)
{
    unsigned i8 = (blockIdx.x * 256u + threadIdx.x) * 8u;
    if (i8 < 4194304u) {
        const float4* s4 = (const float4*)(x + i8);
        float4 a = s4[0], b = s4[1];
        uint4 o = {pack2bf(a.x, a.y), pack2bf(a.z, a.w),
                   pack2bf(b.x, b.y), pack2bf(b.z, b.w)};
        *(uint4*)(x_bf + i8) = o;
    } else if (i8 < 12582912u) {
        unsigned i = i8 - 4194304u;
        int c = i >> 12, j0 = i & 4095;
        const float inv_n = 1.0f / 4096.0f;
        float v[8];
        if (c < 1024) {
            if (c == 0) {
                #pragma unroll
                for (int u = 0; u < 8; ++u) v[u] = inv_n;
            } else {
                #pragma unroll
                for (int u = 0; u < 8; ++u) {
                    int t = (c * (j0 + u)) & 4095;
                    v[u] = 2.0f * inv_n * cosf((float)t * (PI2 / 4096.0f));
                }
            }
        } else {
            int m = c - 1024;
            #pragma unroll
            for (int u = 0; u < 8; ++u) {
                int t = (m * (j0 + u)) & 4095;
                v[u] = -2.0f * inv_n * sinf((float)t * (PI2 / 4096.0f));
            }
        }
        uint4 o = {pack2bf(v[0], v[1]), pack2bf(v[2], v[3]),
                   pack2bf(v[4], v[5]), pack2bf(v[6], v[7])};
        *(uint4*)(B1 + i) = o;
    } else if (i8 < 16777216u) {
        unsigned i = i8 - 12582912u;
        int t = i >> 11, c = i & 2047;
        const float* src = (c < 1024) ? (Vr + t * 1024 + c)
                                      : (Vi + t * 1024 + (c - 1024));
        float4 a = ((const float4*)src)[0], b = ((const float4*)src)[1];
        uint4 o = {pack2bf(a.x, a.y), pack2bf(a.z, a.w),
                   pack2bf(b.x, b.y), pack2bf(b.z, b.w)};
        *(uint4*)(Vcat + i) = o;
    } else if (i8 < 18874368u) {
        unsigned i = i8 - 16777216u;
        int k = i >> 10, p0 = i & 1023;
        float sk = S[k];
        const float inv_n = 1.0f / 2048.0f;
        float v[8];
        #pragma unroll
        for (int u = 0; u < 8; ++u) {
            int p = p0 + u;
            float val;
            if (p == 0) val = inv_n;
            else if (p < 512) {
                int t = (p * k) & 2047;
                val = 2.0f * inv_n * cosf((float)t * (PI2 / 2048.0f));
            } else {
                int q = p - 512;
                int t = (q * k) & 2047;
                val = -2.0f * inv_n * sinf((float)t * (PI2 / 2048.0f));
            }
            v[u] = val * sk;
        }
        uint4 o = {pack2bf(v[0], v[1]), pack2bf(v[2], v[3]),
                   pack2bf(v[4], v[5]), pack2bf(v[6], v[7])};
        *(uint4*)(B2t + i) = o;
    } else if (i8 < 23068672u) {
        unsigned i = i8 - 18874368u;
        int o_ = i >> 10, c = i & 1023;
        const float* src = (c < 512) ? (Ur + o_ * 512 + c)
                                     : (Ui + o_ * 512 + (c - 512));
        float4 a = ((const float4*)src)[0], b = ((const float4*)src)[1];
        uint4 o = {pack2bf(a.x, a.y), pack2bf(a.z, a.w),
                   pack2bf(b.x, b.y), pack2bf(b.z, b.w)};
        *(uint4*)(Ucat + i) = o;
    } else {
        // out = bias broadcast (final GEMM accumulates atomically on top)
        unsigned i = i8 - 23068672u;
        int c = i & 4095;
        float4 b0 = *(const float4*)(bias + c);
        float4 b1 = *(const float4*)(bias + c + 4);
        *(float4*)(outF + i)     = b0;
        *(float4*)(outF + i + 4) = b1;
    }
}

// ---------------------------------------------------------------------------
// Shared 128x128 MFMA tile core, BK=64, XOR-swizzled LDS (round-4 proven).
// ---------------------------------------------------------------------------
__device__ __forceinline__ void tile_core(
    const short* __restrict__ A, int lda,
    const short* __restrict__ B, int ldb, int K,
    short* As, short* Bs, int bm, int bn, f32x4 (&acc)[4][4])
{
    const int tid  = threadIdx.x;
    const int wave = tid >> 6;
    const int lane = tid & 63;
    const int wm   = (wave >> 1) << 6;
    const int wn   = (wave & 1) << 6;
    const int l16  = lane & 15;
    const int quad = lane >> 4;
    const int rk   = l16 & 7;

    int aoff[4], boff[4], loff[4];
    #pragma unroll
    for (int p = 0; p < 4; ++p) {
        int L   = p * 256 + wave * 64 + lane;
        int row = L >> 3;
        int swz = (L & 7) ^ (row & 7);
        aoff[p] = (bm + row) * lda + swz * 8;
        boff[p] = (bn + row) * ldb + swz * 8;
        loff[p] = L * 8;
    }

    for (int k0 = 0; k0 < K; k0 += 64) {
        __syncthreads();
        #pragma unroll
        for (int p = 0; p < 4; ++p) g2l16(A + aoff[p] + k0, As + loff[p]);
        #pragma unroll
        for (int p = 0; p < 4; ++p) g2l16(B + boff[p] + k0, Bs + loff[p]);
        __syncthreads();

        #pragma unroll
        for (int h = 0; h < 2; ++h) {
            const int cs8 = ((((h << 2) | quad) ^ rk) << 3);
            bf16x8 b[4];
            #pragma unroll
            for (int nt = 0; nt < 4; ++nt)
                b[nt] = *(const bf16x8*)(Bs + (wn + nt * 16 + l16) * 64 + cs8);
            #pragma unroll
            for (int mt = 0; mt < 4; ++mt) {
                bf16x8 a = *(const bf16x8*)(As + (wm + mt * 16 + l16) * 64 + cs8);
                #pragma unroll
                for (int nt = 0; nt < 4; ++nt)
                    acc[mt][nt] = __builtin_amdgcn_mfma_f32_16x16x32_bf16(
                        a, b[nt], acc[mt][nt], 0, 0, 0);
            }
        }
    }
}

__device__ __forceinline__ void store_tile_bf16(
    f32x4 (&acc)[4][4], short* __restrict__ C, int ldc, int bm, int bn)
{
    const int tid  = threadIdx.x;
    const int wave = tid >> 6;
    const int lane = tid & 63;
    const int wm   = (wave >> 1) << 6;
    const int wn   = (wave & 1) << 6;
    const int l16  = lane & 15;
    const int quad = lane >> 4;
    #pragma unroll
    for (int nt = 0; nt < 4; ++nt) {
        int col = bn + wn + nt * 16 + l16;
        #pragma unroll
        for (int mt = 0; mt < 4; ++mt) {
            int rowb = bm + wm + mt * 16 + quad * 4;
            #pragma unroll
            for (int r = 0; r < 4; ++r)
                C[(size_t)(rowb + r) * ldc + col] = f2bf(acc[mt][nt][r]);
        }
    }
}

// Fragment-layout store: 8 coalesced uint4 per thread (round-7 proven).
__device__ __forceinline__ void store_frag(
    f32x4 (&acc)[4][4], short* __restrict__ planeTile)
{
    uint4* p = (uint4*)planeTile;
    const int tid = threadIdx.x;
    #pragma unroll
    for (int c = 0; c < 8; ++c) {
        int nt = c >> 1, mt0 = (c & 1) * 2;
        uint4 o = {pack2bf(acc[mt0][nt][0],     acc[mt0][nt][1]),
                   pack2bf(acc[mt0][nt][2],     acc[mt0][nt][3]),
                   pack2bf(acc[mt0 + 1][nt][0], acc[mt0 + 1][nt][1]),
                   pack2bf(acc[mt0 + 1][nt][2], acc[mt0 + 1][nt][3])};
        p[c * 256 + tid] = o;
    }
}

// Reduce one fragment chunk (tile, c) across SK planes -> row-major output.
template <bool OUT_F32>
__device__ __forceinline__ void reduce_unit(
    const short* __restrict__ P, size_t planeU4, int SK,
    int tile, int c, int tilesX, void* __restrict__ Out, int ldc,
    const float* __restrict__ bias)
{
    const int bm = (tile / tilesX) << 7;
    const int bn = (tile % tilesX) << 7;
    const int tid  = threadIdx.x;
    const int wave = tid >> 6;
    const int lane = tid & 63;
    const int wm   = (wave >> 1) << 6;
    const int wn   = (wave & 1) << 6;
    const int l16  = lane & 15;
    const int quad = lane >> 4;
    const int nt   = c >> 1, mt0 = (c & 1) * 2;

    const uint4* P4 = (const uint4*)P;
    const size_t base = (size_t)tile * 2048 + (size_t)c * 256 + tid;
    float f[8] = {0, 0, 0, 0, 0, 0, 0, 0};
    for (int z = 0; z < SK; ++z) {
        uint4 v = P4[(size_t)z * planeU4 + base];
        f[0] += bflo(v.x); f[1] += bfhi(v.x);
        f[2] += bflo(v.y); f[3] += bfhi(v.y);
        f[4] += bflo(v.z); f[5] += bfhi(v.z);
        f[6] += bflo(v.w); f[7] += bfhi(v.w);
    }
    const int col = bn + wn + nt * 16 + l16;
    float bv = 0.f;
    if (OUT_F32) bv = bias[col];
    #pragma unroll
    for (int j = 0; j < 8; ++j) {
        int mt  = mt0 + (j >> 2);
        int row = bm + wm + mt * 16 + quad * 4 + (j & 3);
        if (OUT_F32)
            ((float*)Out)[(size_t)row * ldc + col] = f[j] + bv;
        else
            ((short*)Out)[(size_t)row * ldc + col] = f2bf(f[j]);
    }
}

// ---------------------------------------------------------------------------
// Merged s1 + M2 dispatch, 1-D grid of 1024 blocks, XCD-swizzled (round-9).
// ---------------------------------------------------------------------------
__global__ __launch_bounds__(256, 4) void gemm_s1_m2(
    const short* __restrict__ x_bf, const short* __restrict__ B1,
    short* __restrict__ Pp,
    const short* __restrict__ Ucat, const short* __restrict__ B2t,
    short* __restrict__ M2)
{
    __shared__ __align__(16) short As[128 * 64];
    __shared__ __align__(16) short Bs[128 * 64];

    f32x4 acc[4][4];
    #pragma unroll
    for (int i = 0; i < 4; ++i)
        #pragma unroll
        for (int j = 0; j < 4; ++j)
            acc[i][j] = (f32x4){0.f, 0.f, 0.f, 0.f};

    const int u = xcd_swizzle((int)blockIdx.x, (int)gridDim.x);
    if (u < 512) {
        int z = u >> 7, tile = u & 127;
        int bm = (tile >> 4) << 7, bn = (tile & 15) << 7;
        tile_core(x_bf + z * 1024, 4096, B1 + z * 1024, 4096, 1024,
                  As, Bs, bm, bn, acc);
        store_frag(acc, Pp + (size_t)z * 2097152 + (size_t)tile * 16384);
    } else {
        int m2u = u - 512;                    // 32 m-tiles x 16 n-tiles
        int bm = (m2u >> 4) << 7, bn = (m2u & 15) << 7;
        tile_core(Ucat, 1024, B2t, 1024, 1024, As, Bs, bm, bn, acc);
        store_tile_bf16(acc, M2, 2048, bm, bn);
    }
}

// ---------------------------------------------------------------------------
// Split-K GEMM into fragment-layout bf16 partial planes (round-9 proven).
// ---------------------------------------------------------------------------
__global__ __launch_bounds__(256, 4) void gemm_sk_frag(
    const short* __restrict__ A, int lda,
    const short* __restrict__ B, int ldb,
    short* __restrict__ P, size_t planeShorts, int Kpart,
    int tileShift, int tilesXShift)
{
    __shared__ __align__(16) short As[128 * 64];
    __shared__ __align__(16) short Bs[128 * 64];

    f32x4 acc[4][4];
    #pragma unroll
    for (int i = 0; i < 4; ++i)
        #pragma unroll
        for (int j = 0; j < 4; ++j)
            acc[i][j] = (f32x4){0.f, 0.f, 0.f, 0.f};

    const int u    = xcd_swizzle((int)blockIdx.x, (int)gridDim.x);
    const int z    = u >> tileShift;
    const int tile = u & ((1 << tileShift) - 1);
    const int bm   = (tile >> tilesXShift) << 7;
    const int bn   = (tile & ((1 << tilesXShift) - 1)) << 7;

    tile_core(A + (size_t)z * Kpart, lda, B + (size_t)z * Kpart, ldb, Kpart,
              As, Bs, bm, bn, acc);
    store_frag(acc, P + (size_t)z * planeShorts + (size_t)tile * 16384);
}

// ---------------------------------------------------------------------------
// Split-K GEMM with f32 ATOMIC epilogue: each z-block adds its partial tile
// directly into Out (pre-initialized with bias by aux). Removes the final
// reduce dispatch. unsafeAtomicAdd -> native global_atomic_add_f32.
// ---------------------------------------------------------------------------
__global__ __launch_bounds__(256, 4) void gemm_sk_atomic(
    const short* __restrict__ A, int lda,
    const short* __restrict__ B, int ldb,
    float* __restrict__ Out, int Kpart,
    int tileShift, int tilesXShift)
{
    __shared__ __align__(16) short As[128 * 64];
    __shared__ __align__(16) short Bs[128 * 64];

    f32x4 acc[4][4];
    #pragma unroll
    for (int i = 0; i < 4; ++i)
        #pragma unroll
        for (int j = 0; j < 4; ++j)
            acc[i][j] = (f32x4){0.f, 0.f, 0.f, 0.f};

    const int u    = xcd_swizzle((int)blockIdx.x, (int)gridDim.x);
    const int z    = u >> tileShift;
    const int tile = u & ((1 << tileShift) - 1);
    const int bm   = (tile >> tilesXShift) << 7;
    const int bn   = (tile & ((1 << tilesXShift) - 1)) << 7;

    tile_core(A + (size_t)z * Kpart, lda, B + (size_t)z * Kpart, ldb, Kpart,
              As, Bs, bm, bn, acc);

    const int tid  = threadIdx.x;
    const int wave = tid >> 6;
    const int lane = tid & 63;
    const int wm   = (wave >> 1) << 6;
    const int wn   = (wave & 1) << 6;
    const int l16  = lane & 15;
    const int quad = lane >> 4;

    #pragma unroll
    for (int nt = 0; nt < 4; ++nt) {
        int col = bn + wn + nt * 16 + l16;
        #pragma unroll
        for (int mt = 0; mt < 4; ++mt) {
            int rowb = bm + wm + mt * 16 + quad * 4;
            #pragma unroll
            for (int r = 0; r < 4; ++r)
                unsafeAtomicAdd(Out + (size_t)(rowb + r) * 4096 + col,
                                acc[mt][nt][r]);
        }
    }
}

template <bool OUT_F32>
__global__ __launch_bounds__(256) void reduce_frag(
    const short* __restrict__ P, size_t planeShorts, int SK,
    int tilesX, void* __restrict__ Out, int ldc,
    const float* __restrict__ bias)
{
    reduce_unit<OUT_F32>(P, planeShorts >> 3, SK,
                         (int)(blockIdx.x >> 3), (int)(blockIdx.x & 7),
                         tilesX, Out, ldc, bias);
}

// ---------------------------------------------------------------------------
// Direct GEMM for the small-ws fallback path (round-7 proven)
// ---------------------------------------------------------------------------
template <bool OUT_F32>
__global__ __launch_bounds__(256, 4) void gemm_direct(
    const short* __restrict__ A, int lda,
    const short* __restrict__ B, int ldb,
    void* __restrict__ Cv, int ldc,
    const float* __restrict__ bias, int K)
{
    __shared__ __align__(16) short As[128 * 64];
    __shared__ __align__(16) short Bs[128 * 64];

    f32x4 acc[4][4];
    #pragma unroll
    for (int i = 0; i < 4; ++i)
        #pragma unroll
        for (int j = 0; j < 4; ++j)
            acc[i][j] = (f32x4){0.f, 0.f, 0.f, 0.f};

    const int bm = blockIdx.y << 7;
    const int bn = blockIdx.x << 7;
    tile_core(A, lda, B, ldb, K, As, Bs, bm, bn, acc);

    const int tid  = threadIdx.x;
    const int wave = tid >> 6;
    const int lane = tid & 63;
    const int wm   = (wave >> 1) << 6;
    const int wn   = (wave & 1) << 6;
    const int l16  = lane & 15;
    const int quad = lane >> 4;

    if (OUT_F32) {
        float* C = (float*)Cv;
        #pragma unroll
        for (int nt = 0; nt < 4; ++nt) {
            int col = bn + wn + nt * 16 + l16;
            float bv = bias ? bias[col] : 0.f;
            #pragma unroll
            for (int mt = 0; mt < 4; ++mt) {
                int rowb = bm + wm + mt * 16 + quad * 4;
                #pragma unroll
                for (int r = 0; r < 4; ++r)
                    C[(size_t)(rowb + r) * ldc + col] = acc[mt][nt][r] + bv;
            }
        }
    } else {
        store_tile_bf16(acc, (short*)Cv, ldc, bm, bn);
    }
}

extern "C" void kernel_launch(void* const* d_in, const int* in_sizes, int n_in,
                              void* d_out, int out_size, void* d_ws, size_t ws_size,
                              hipStream_t stream) {
    const float* x    = (const float*)d_in[0];
    const float* Ur   = (const float*)d_in[1];
    const float* Ui   = (const float*)d_in[2];
    const float* S    = (const float*)d_in[3];
    const float* Vr   = (const float*)d_in[4];
    const float* Vi   = (const float*)d_in[5];
    const float* bias = (const float*)d_in[6];
    float* out = (float*)d_out;

    short* ws   = (short*)d_ws;
    short* x_bf = ws;                                  // 1024*4096
    short* B1   = x_bf + (size_t)1024 * 4096;          // 2048*4096
    short* Vcat = B1   + (size_t)2048 * 4096;          // 2048*2048
    short* B2t  = Vcat + (size_t)2048 * 2048;          // 2048*1024
    short* Ucat = B2t  + (size_t)2048 * 1024;          // 4096*1024
    short* Xp   = Ucat + (size_t)4096 * 1024;          // 1024*2048
    short* T1   = Xp   + (size_t)1024 * 2048;          // 1024*2048
    short* M2   = T1   + (size_t)1024 * 2048;          // 4096*2048
    short* Pp   = M2   + (size_t)4096 * 2048;          // partials: 16.78M shorts

    const size_t need = (size_t)((char*)(Pp + (size_t)8 * 1024 * 2048) - (char*)d_ws);

    // aux also pre-initializes out = bias (consumed by the atomic epilogue)
    aux_all8<<<dim3(13312), 256, 0, stream>>>(
        x, Ur, Ui, S, Vr, Vi, x_bf, B1, Vcat, B2t, Ucat, bias, out);

    if (ws_size >= need) {
        // s1 (SK=4, Kpart=1024, frag partials) + M2 (direct): 1024 blocks
        gemm_s1_m2<<<dim3(1024), 256, 0, stream>>>(
            x_bf, B1, Pp, Ucat, B2t, M2);
        reduce_frag<false><<<dim3(1024), 256, 0, stream>>>(
            Pp, (size_t)2097152, 4, 16, Xp, 2048, nullptr);

        // Stage 2: T1 = X' @ Vcat^T (SK=8, Kpart=256 -> 1024 blocks)
        gemm_sk_frag<<<dim3(1024), 256, 0, stream>>>(
            Xp, 2048, Vcat, 2048, Pp, (size_t)2097152, 256, 7, 4);
        reduce_frag<false><<<dim3(1024), 256, 0, stream>>>(
            Pp, (size_t)2097152, 8, 16, T1, 2048, nullptr);

        // Final: out += T1 @ M2^T (SK=4, Kpart=512 -> 1024 blocks, atomic)
        gemm_sk_atomic<<<dim3(1024), 256, 0, stream>>>(
            T1, 2048, M2, 2048, out, 512, 8, 5);
    } else {
        gemm_direct<false><<<dim3(16, 8), 256, 0, stream>>>(
            x_bf, 4096, B1, 4096, Xp, 2048, nullptr, 4096);
        gemm_direct<false><<<dim3(16, 8), 256, 0, stream>>>(
            Xp, 2048, Vcat, 2048, T1, 2048, nullptr, 2048);
        gemm_direct<false><<<dim3(16, 32), 256, 0, stream>>>(
            Ucat, 1024, B2t, 1024, M2, 2048, nullptr, 1024);
        gemm_direct<true><<<dim3(32, 8), 256, 0, stream>>>(
            T1, 2048, M2, 2048, out, 4096, bias, 2048);
    }
}